// Round 17
// baseline (1057.104 us; speedup 1.0000x reference)
//
#include <hip/hip_runtime.h>
#include <hip/hip_bf16.h>

#define BB 64
#define SS 2048
#define II 64
#define HH 128

typedef _Float16 half8 __attribute__((ext_vector_type(8)));
typedef float f32x4 __attribute__((ext_vector_type(4)));

#define LOG2E 1.44269504088896340736f

__device__ __forceinline__ float sigm(float x) { return 1.0f / (1.0f + __expf(-x)); }

// wx0[b,s,j] = sum_i x[b,s,i] * w0[i,j]   (layout [b][s][j])
__global__ __launch_bounds__(256, 4)
void wx0_kernel(const float* __restrict__ x, const float* __restrict__ w0,
                float* __restrict__ wx0) {
  __shared__ float xs[32][64];
  const int tid = threadIdx.x;
  const int j = tid & (HH - 1);
  const int rh = tid >> 7;
  const long row0 = (long)blockIdx.x * 32;

  float w0c[II];
#pragma unroll
  for (int i = 0; i < II; ++i) w0c[i] = w0[i * HH + j];

  const float4* xg = (const float4*)(x + row0 * II);
  float4* xsv = (float4*)&xs[0][0];
  xsv[tid] = xg[tid];
  xsv[tid + 256] = xg[tid + 256];
  __syncthreads();

#pragma unroll
  for (int rp = 0; rp < 16; ++rp) {
    int r = rp * 2 + rh;
    float acc = 0.f;
#pragma unroll
    for (int i = 0; i < II; i += 4) {
      float4 xv = *(const float4*)&xs[r][i];
      acc += w0c[i] * xv.x + w0c[i + 1] * xv.y + w0c[i + 2] * xv.z +
             w0c[i + 3] * xv.w;
    }
    wx0[(row0 + r) * HH + j] = acc;
  }
}

// Fused 2-layer scan == R11 structure (measured optimum, 1008 cyc/step)
// with two chain-stripping changes:
//  1. wx comes from GLOBAL via a 1-step register prefetch pipeline (load
//     wx[t+2] at top of step t) -- deletes the per-step wxb ds_read, all 32
//     chunk-restage sequences and their extra barrier+drain, and 32 KB LDS.
//  2. MFMA issue order A,C,B (A completes earliest; gate0 source-ordered
//     first, so only gate1 -- fed by the last-completing accB -- is in the
//     post-pipe tail).
// Structure: one block per batch, 8 waves, layer-skewed
//   iter t: h0[t+1] = G0(h0[t], wx[t+1]);  h1[t] = G1(h1[t-1], h0@w1 + h1@u1)
// Wave w owns column-tile w for A=h0@u0, B=h0@w1, C=h1@u1 (12 MFMA, 2/SIMD).
// A-fragments exec-masked to lanes n==0 (only D-row 0 real -> valid results
// on g==0 lanes reg 0; g0 lanes do all writes). Double-buffered h in LDS,
// one barrier per step.
__global__ __launch_bounds__(512, 1)
void scan_kernel(const float* __restrict__ wx0,
                 const float* __restrict__ u0, const float* __restrict__ bg0,
                 const float* __restrict__ bu0, const float* __restrict__ zeta0,
                 const float* __restrict__ nu0, const float* __restrict__ lambd0,
                 const float* __restrict__ gamma0,
                 const float* __restrict__ w1, const float* __restrict__ u1,
                 const float* __restrict__ bg1, const float* __restrict__ bu1,
                 const float* __restrict__ zeta1, const float* __restrict__ nu1,
                 const float* __restrict__ lambd1, const float* __restrict__ gamma1,
                 float* __restrict__ out1, float* __restrict__ hn) {
  const int b = blockIdx.x;
  const int tid = threadIdx.x;
  const int w = tid >> 6;              // wave = column tile (0..7)
  const int l = tid & 63;
  const int g = l >> 4;
  const int n = l & 15;
  const int c = 16 * w + n;            // this lane's duty column

  // ---- weight B-fragments (f16) for tile w: elem i -> k = 32kt + kmap(g,i)
  half8 wfA[4], wfB[4], wfC[4];
#pragma unroll
  for (int kt = 0; kt < 4; ++kt) {
    half8 fa, fb, fc;
#pragma unroll
    for (int i = 0; i < 8; ++i) {
      int k = 32 * kt + (i < 4 ? 4 * g + i : 16 + 4 * g + (i - 4));
      fa[i] = (_Float16)u0[k * HH + c];
      fb[i] = (_Float16)w1[k * HH + c];
      fc[i] = (_Float16)u1[k * HH + c];
    }
    wfA[kt] = fa; wfB[kt] = fb; wfC[kt] = fc;
  }

  // ---- gate constants, both layers (lane gates col c for L0 and L1)
  const float sz0 = sigm(zeta0[0]), sn0 = sigm(nu0[0]);
  const float gc0 = fminf(fmaxf(gamma0[0], 0.f), 1.f);
  const float kc0 = (1.f - gc0) * lambd0[0];
  const float sz1 = sigm(zeta1[0]), sn1 = sigm(nu1[0]);
  const float gc1 = fminf(fmaxf(gamma1[0], 0.f), 1.f);
  const float kc1 = (1.f - gc1) * lambd1[0];
  const float ebg0 = -LOG2E * bg0[c];
  const float ebu0 = -2.f * LOG2E * bu0[c];
  const float ebg1 = -LOG2E * bg1[c];
  const float ebu1 = -2.f * LOG2E * bu1[c];

  auto gate = [](float pre, float hp, float eg, float eu, float sz, float sn,
                 float gc, float kc) -> float {
    float p  = __builtin_amdgcn_exp2f(__builtin_fmaf(pre, -LOG2E, eg));
    float qq = __builtin_amdgcn_exp2f(__builtin_fmaf(pre, -2.f * LOG2E, eu));
    float opp = 1.f + p, opq = 1.f + qq, omq = 1.f - qq;
    float t1 = __builtin_fmaf(sn, opp, sz * p);
    float num = __builtin_fmaf(hp, opq, t1 * omq);
    float hnew = num * __builtin_amdgcn_rcpf(opp * opq);
    return __builtin_fmaf(gc, hnew, kc);
  };

  // fragment-order packed h: [buf][layer][160 halves] -- only LDS left
  __shared__ __align__(16) _Float16 Hpk[2][2][160];

  const float* wxg = wx0 + (size_t)b * SS * HH;
  float* outg = out1 + (size_t)b * SS * HH;

  // widx(c): fragment-order slot for column c (inverse of kmap)
  const int wkt = c >> 5;
  const int wr_ = c & 31;
  const int widx = (wkt * 4 + ((wr_ & 15) >> 2)) * 8 + ((wr_ >> 4) << 2) + (wr_ & 3);
  const int rbase = 8 * g;

  // ---- prologue: h0[0] = G0(0, wx[0]); h1[-1] = 0; prime wx pipeline
  float hp0, hp1 = 0.f;
  {
    float h00 = gate(wxg[c], 0.f, ebg0, ebu0, sz0, sn0, gc0, kc0);
    hp0 = h00;
    if (g == 0) {
      Hpk[0][0][widx] = (_Float16)h00;
      Hpk[0][1][widx] = (_Float16)0.f;
    }
  }
  float wx_cur = wxg[(size_t)1 * HH + c];   // wx[t+1] for t=0
  asm volatile("s_waitcnt lgkmcnt(0)" ::: "memory");
  __builtin_amdgcn_s_barrier();

  const f32x4 zero = {0.f, 0.f, 0.f, 0.f};

  // persistent A-fragments: zero on n!=0 lanes forever (their D-rows unused)
  half8 a0[4], a1[4];
#pragma unroll
  for (int kt = 0; kt < 4; ++kt) {
    a0[kt] = (half8)(_Float16)0.f;
    a1[kt] = (half8)(_Float16)0.f;
  }

  for (int t = 0; t < SS; ++t) {
    const int rd = t & 1, wb = rd ^ 1;

    // ---- prefetch wx[t+2] (used next iter; ~1 full step of hiding)
    int rown = t + 2 < SS ? t + 2 : SS - 1;
    float wx_nxt = wxg[(size_t)rown * HH + c];

    // ---- A-fragments: only lanes n==0 carry row 0 (64 B/instr delivered)
    if (n == 0) {
#pragma unroll
      for (int kt = 0; kt < 4; ++kt) {
        a1[kt] = __builtin_bit_cast(half8,
                   *(const uint4*)&Hpk[rd][1][kt * 32 + rbase]);
        a0[kt] = __builtin_bit_cast(half8,
                   *(const uint4*)&Hpk[rd][0][kt * 32 + rbase]);
      }
    }

    // ---- 3 matvec chains, K chained through the C operand.
    //      A issued first per kt -> accA completes earliest; accB last.
    f32x4 accA, accB, accC;
#pragma unroll
    for (int kt = 0; kt < 4; ++kt) {
      accA = __builtin_amdgcn_mfma_f32_16x16x32_f16(a0[kt], wfA[kt], kt ? accA : zero, 0, 0, 0);
      accC = __builtin_amdgcn_mfma_f32_16x16x32_f16(a1[kt], wfC[kt], kt ? accC : zero, 0, 0, 0);
      accB = __builtin_amdgcn_mfma_f32_16x16x32_f16(a0[kt], wfB[kt], kt ? accB : zero, 0, 0, 0);
    }

    // ---- gate 0 first (accA ready earliest); valid on g==0 lanes only
    float pre0 = accA[0] + wx_cur;
    float hc0 = gate(pre0, hp0, ebg0, ebu0, sz0, sn0, gc0, kc0);
    hp0 = hc0;
    if (g == 0) Hpk[wb][0][widx] = (_Float16)hc0;

    // ---- gate 1 (accB is the last-completing chain -> only tail work)
    float pre1 = accB[0] + accC[0];
    float hc1 = gate(pre1, hp1, ebg1, ebu1, sz1, sn1, gc1, kc1);
    hp1 = hc1;
    if (g == 0) {
      Hpk[wb][1][widx] = (_Float16)hc1;
      outg[(size_t)t * HH + c] = hc1;
      if (t == SS - 2) hn[b * HH + c] = hc0;                 // h0[SS-1]
      if (t == SS - 1) hn[BB * HH + b * HH + c] = hc1;       // h1[SS-1]
    }

    wx_cur = wx_nxt;

    asm volatile("s_waitcnt lgkmcnt(0)" ::: "memory");
    __builtin_amdgcn_s_barrier();
  }
}

extern "C" void kernel_launch(void* const* d_in, const int* in_sizes, int n_in,
                              void* d_out, int out_size, void* d_ws, size_t ws_size,
                              hipStream_t stream) {
  const float* x      = (const float*)d_in[0];
  const float* w0     = (const float*)d_in[1];
  const float* u0     = (const float*)d_in[2];
  const float* bg0    = (const float*)d_in[3];
  const float* bu0    = (const float*)d_in[4];
  const float* zeta0  = (const float*)d_in[5];
  const float* nu0    = (const float*)d_in[6];
  const float* lambd0 = (const float*)d_in[7];
  const float* gamma0 = (const float*)d_in[8];
  const float* w1     = (const float*)d_in[9];
  const float* u1     = (const float*)d_in[10];
  const float* bg1    = (const float*)d_in[11];
  const float* bu1    = (const float*)d_in[12];
  const float* zeta1  = (const float*)d_in[13];
  const float* nu1    = (const float*)d_in[14];
  const float* lambd1 = (const float*)d_in[15];
  const float* gamma1 = (const float*)d_in[16];

  float* out = (float*)d_out;                     // out1: [B,S,H]
  float* hn  = out + (size_t)BB * SS * HH;        // h_n:  [2,B,H]
  float* wx0 = (float*)d_ws;                      // scratch: [B,S,H] fp32 (64 MB)

  wx0_kernel<<<(BB * SS) / 32, 256, 0, stream>>>(x, w0, wx0);
  scan_kernel<<<BB, 512, 0, stream>>>(wx0, u0, bg0, bu0, zeta0, nu0, lambd0,
                                      gamma0, w1, u1, bg1, bu1, zeta1, nu1,
                                      lambd1, gamma1, out, hn);
}

// Round 18
// 899.338 us; speedup vs baseline: 1.1754x; 1.1754x over previous
//
#include <hip/hip_runtime.h>
#include <hip/hip_bf16.h>

#define BB 64
#define SS 2048
#define II 64
#define HH 128
#define CH 64   // timestep chunk of wx staged in LDS

typedef _Float16 half8 __attribute__((ext_vector_type(8)));
typedef float f32x4 __attribute__((ext_vector_type(4)));

#define LOG2E 1.44269504088896340736f

__device__ __forceinline__ float sigm(float x) { return 1.0f / (1.0f + __expf(-x)); }

// wx0[b,s,j] = sum_i x[b,s,i] * w0[i,j]   (layout [b][s][j])
__global__ __launch_bounds__(256, 4)
void wx0_kernel(const float* __restrict__ x, const float* __restrict__ w0,
                float* __restrict__ wx0) {
  __shared__ float xs[32][64];
  const int tid = threadIdx.x;
  const int j = tid & (HH - 1);
  const int rh = tid >> 7;
  const long row0 = (long)blockIdx.x * 32;

  float w0c[II];
#pragma unroll
  for (int i = 0; i < II; ++i) w0c[i] = w0[i * HH + j];

  const float4* xg = (const float4*)(x + row0 * II);
  float4* xsv = (float4*)&xs[0][0];
  xsv[tid] = xg[tid];
  xsv[tid + 256] = xg[tid + 256];
  __syncthreads();

#pragma unroll
  for (int rp = 0; rp < 16; ++rp) {
    int r = rp * 2 + rh;
    float acc = 0.f;
#pragma unroll
    for (int i = 0; i < II; i += 4) {
      float4 xv = *(const float4*)&xs[r][i];
      acc += w0c[i] * xv.x + w0c[i + 1] * xv.y + w0c[i + 2] * xv.z +
             w0c[i + 3] * xv.w;
    }
    wx0[(row0 + r) * HH + j] = acc;
  }
}

// Fused 2-layer scan == R11 (measured optimum, 1008 cyc/step) with ONE
// change: wxb is DOUBLE-BUFFERED. Chunk restage becomes global->reg
// prefetch at q==CH-2 (one step of hiding) + reg->LDS write into the other
// buffer at q==CH-1 BEFORE the regular step barrier -- deleting the 32
// extra chunk-boundary barriers+drains and their post-barrier HBM stalls.
// Structure: one block per batch, 8 waves, layer-skewed
//   iter t: h0[t+1] = G0(h0[t], wx[t+1]);  h1[t] = G1(h1[t-1], h0@w1 + h1@u1)
// Wave w owns column-tile w for A=h0@u0, B=h0@w1, C=h1@u1 (12 MFMA, 2/SIMD).
// A-fragments exec-masked to lanes n==0 (only D-row 0 real -> valid results
// on g==0 lanes reg 0; g0 lanes do all writes). Double-buffered h in LDS,
// one barrier per step.
__global__ __launch_bounds__(512, 1)
void scan_kernel(const float* __restrict__ wx0,
                 const float* __restrict__ u0, const float* __restrict__ bg0,
                 const float* __restrict__ bu0, const float* __restrict__ zeta0,
                 const float* __restrict__ nu0, const float* __restrict__ lambd0,
                 const float* __restrict__ gamma0,
                 const float* __restrict__ w1, const float* __restrict__ u1,
                 const float* __restrict__ bg1, const float* __restrict__ bu1,
                 const float* __restrict__ zeta1, const float* __restrict__ nu1,
                 const float* __restrict__ lambd1, const float* __restrict__ gamma1,
                 float* __restrict__ out1, float* __restrict__ hn) {
  const int b = blockIdx.x;
  const int tid = threadIdx.x;
  const int w = tid >> 6;              // wave = column tile (0..7)
  const int l = tid & 63;
  const int g = l >> 4;
  const int n = l & 15;
  const int c = 16 * w + n;            // this lane's duty column

  // ---- weight B-fragments (f16) for tile w: elem i -> k = 32kt + kmap(g,i)
  half8 wfA[4], wfB[4], wfC[4];
#pragma unroll
  for (int kt = 0; kt < 4; ++kt) {
    half8 fa, fb, fc;
#pragma unroll
    for (int i = 0; i < 8; ++i) {
      int k = 32 * kt + (i < 4 ? 4 * g + i : 16 + 4 * g + (i - 4));
      fa[i] = (_Float16)u0[k * HH + c];
      fb[i] = (_Float16)w1[k * HH + c];
      fc[i] = (_Float16)u1[k * HH + c];
    }
    wfA[kt] = fa; wfB[kt] = fb; wfC[kt] = fc;
  }

  // ---- gate constants, both layers (lane gates col c for L0 and L1)
  const float sz0 = sigm(zeta0[0]), sn0 = sigm(nu0[0]);
  const float gc0 = fminf(fmaxf(gamma0[0], 0.f), 1.f);
  const float kc0 = (1.f - gc0) * lambd0[0];
  const float sz1 = sigm(zeta1[0]), sn1 = sigm(nu1[0]);
  const float gc1 = fminf(fmaxf(gamma1[0], 0.f), 1.f);
  const float kc1 = (1.f - gc1) * lambd1[0];
  const float ebg0 = -LOG2E * bg0[c];
  const float ebu0 = -2.f * LOG2E * bu0[c];
  const float ebg1 = -LOG2E * bg1[c];
  const float ebu1 = -2.f * LOG2E * bu1[c];

  auto gate = [](float pre, float hp, float eg, float eu, float sz, float sn,
                 float gc, float kc) -> float {
    float p  = __builtin_amdgcn_exp2f(__builtin_fmaf(pre, -LOG2E, eg));
    float qq = __builtin_amdgcn_exp2f(__builtin_fmaf(pre, -2.f * LOG2E, eu));
    float opp = 1.f + p, opq = 1.f + qq, omq = 1.f - qq;
    float t1 = __builtin_fmaf(sn, opp, sz * p);
    float num = __builtin_fmaf(hp, opq, t1 * omq);
    float hnew = num * __builtin_amdgcn_rcpf(opp * opq);
    return __builtin_fmaf(gc, hnew, kc);
  };

  // fragment-order packed h: [buf][layer][160 halves]
  __shared__ __align__(16) _Float16 Hpk[2][2][160];
  __shared__ __align__(16) float wxb[2][CH * HH];  // 2 x 32 KB, double-buffered

  const float* wxg = wx0 + (size_t)b * SS * HH;
  float* outg = out1 + (size_t)b * SS * HH;

  // widx(c): fragment-order slot for column c (inverse of kmap)
  const int wkt = c >> 5;
  const int wr_ = c & 31;
  const int widx = (wkt * 4 + ((wr_ & 15) >> 2)) * 8 + ((wr_ >> 4) << 2) + (wr_ & 3);
  const int rbase = 8 * g;

  // ---- prologue: stage wx rows 1..64 into buffer 0
  {
    const float4* src = (const float4*)(wxg + HH);
    float4* dst = (float4*)&wxb[0][0];
#pragma unroll
    for (int i = 0; i < 4; ++i) dst[i * 512 + tid] = src[i * 512 + tid];
  }
  // h0[0] = G0(0, wx[0]); h1[-1] = 0
  float hp0, hp1 = 0.f;
  {
    float h00 = gate(wxg[c], 0.f, ebg0, ebu0, sz0, sn0, gc0, kc0);
    hp0 = h00;
    if (g == 0) {
      Hpk[0][0][widx] = (_Float16)h00;
      Hpk[0][1][widx] = (_Float16)0.f;
    }
  }
  asm volatile("s_waitcnt lgkmcnt(0)" ::: "memory");
  __builtin_amdgcn_s_barrier();

  const f32x4 zero = {0.f, 0.f, 0.f, 0.f};

  // persistent A-fragments: zero on n!=0 lanes forever (their D-rows unused)
  half8 a0[4], a1[4];
#pragma unroll
  for (int kt = 0; kt < 4; ++kt) {
    a0[kt] = (half8)(_Float16)0.f;
    a1[kt] = (half8)(_Float16)0.f;
  }

  float4 pf0, pf1, pf2, pf3;   // prefetched next wx chunk (4 float4/thread)

  for (int t = 0; t < SS; ++t) {
    const int rd = t & 1, wb = rd ^ 1;
    const int q = t & (CH - 1);
    const int sel = (t >> 6) & 1;     // current wx buffer

    // ---- prefetch next chunk into regs one step before the boundary:
    //      next chunk (steps t+2..t+65) needs wx rows t+3..t+66
    if (q == CH - 2 && t + 2 < SS) {
#pragma unroll
      for (int i = 0; i < 4; ++i) {
        int flat4 = i * 512 + tid;
        int row = t + 3 + (flat4 >> 5);
        row = row < SS ? row : SS - 1;
        int col4 = flat4 & 31;
        float4 v = *(const float4*)(wxg + (size_t)row * HH + col4 * 4);
        if (i == 0) pf0 = v; else if (i == 1) pf1 = v;
        else if (i == 2) pf2 = v; else pf3 = v;
      }
    }

    // ---- A-fragments: only lanes n==0 carry row 0 (64 B/instr delivered)
    if (n == 0) {
#pragma unroll
      for (int kt = 0; kt < 4; ++kt) {
        a1[kt] = __builtin_bit_cast(half8,
                   *(const uint4*)&Hpk[rd][1][kt * 32 + rbase]);
        a0[kt] = __builtin_bit_cast(half8,
                   *(const uint4*)&Hpk[rd][0][kt * 32 + rbase]);
      }
    }
    float wxv = wxb[sel][q * HH + c];

    // ---- 3 matvec chains, K chained through the MFMA C operand
    f32x4 accA, accB, accC;
#pragma unroll
    for (int kt = 0; kt < 4; ++kt) {
      accA = __builtin_amdgcn_mfma_f32_16x16x32_f16(a0[kt], wfA[kt], kt ? accA : zero, 0, 0, 0);
      accB = __builtin_amdgcn_mfma_f32_16x16x32_f16(a0[kt], wfB[kt], kt ? accB : zero, 0, 0, 0);
      accC = __builtin_amdgcn_mfma_f32_16x16x32_f16(a1[kt], wfC[kt], kt ? accC : zero, 0, 0, 0);
    }

    // ---- gates: valid only on g==0 lanes (D-row 0); g0 does ALL writes
    float pre0 = accA[0] + wxv;
    float hc0 = gate(pre0, hp0, ebg0, ebu0, sz0, sn0, gc0, kc0);
    hp0 = hc0;
    if (g == 0) Hpk[wb][0][widx] = (_Float16)hc0;

    float pre1 = accB[0] + accC[0];
    float hc1 = gate(pre1, hp1, ebg1, ebu1, sz1, sn1, gc1, kc1);
    hp1 = hc1;
    if (g == 0) {
      Hpk[wb][1][widx] = (_Float16)hc1;
      outg[(size_t)t * HH + c] = hc1;
      if (t == SS - 2) hn[b * HH + c] = hc0;                 // h0[SS-1]
      if (t == SS - 1) hn[BB * HH + b * HH + c] = hc1;       // h1[SS-1]
    }

    // ---- boundary: write prefetched chunk into the OTHER buffer before
    //      the regular step barrier (its lgkm drain publishes the writes)
    if (q == CH - 1 && t + 1 < SS) {
      float4* wdst = (float4*)&wxb[sel ^ 1][0];
      wdst[0 * 512 + tid] = pf0;
      wdst[1 * 512 + tid] = pf1;
      wdst[2 * 512 + tid] = pf2;
      wdst[3 * 512 + tid] = pf3;
    }

    asm volatile("s_waitcnt lgkmcnt(0)" ::: "memory");
    __builtin_amdgcn_s_barrier();
  }
}

extern "C" void kernel_launch(void* const* d_in, const int* in_sizes, int n_in,
                              void* d_out, int out_size, void* d_ws, size_t ws_size,
                              hipStream_t stream) {
  const float* x      = (const float*)d_in[0];
  const float* w0     = (const float*)d_in[1];
  const float* u0     = (const float*)d_in[2];
  const float* bg0    = (const float*)d_in[3];
  const float* bu0    = (const float*)d_in[4];
  const float* zeta0  = (const float*)d_in[5];
  const float* nu0    = (const float*)d_in[6];
  const float* lambd0 = (const float*)d_in[7];
  const float* gamma0 = (const float*)d_in[8];
  const float* w1     = (const float*)d_in[9];
  const float* u1     = (const float*)d_in[10];
  const float* bg1    = (const float*)d_in[11];
  const float* bu1    = (const float*)d_in[12];
  const float* zeta1  = (const float*)d_in[13];
  const float* nu1    = (const float*)d_in[14];
  const float* lambd1 = (const float*)d_in[15];
  const float* gamma1 = (const float*)d_in[16];

  float* out = (float*)d_out;                     // out1: [B,S,H]
  float* hn  = out + (size_t)BB * SS * HH;        // h_n:  [2,B,H]
  float* wx0 = (float*)d_ws;                      // scratch: [B,S,H] fp32 (64 MB)

  wx0_kernel<<<(BB * SS) / 32, 256, 0, stream>>>(x, w0, wx0);
  scan_kernel<<<BB, 512, 0, stream>>>(wx0, u0, bg0, bu0, zeta0, nu0, lambd0,
                                      gamma0, w1, u1, bg1, bu1, zeta1, nu1,
                                      lambd1, gamma1, out, hn);
}